// Round 1
// baseline (952.532 us; speedup 1.0000x reference)
//
#include <hip/hip_runtime.h>
#include <math.h>

#define NB 16
#define NT 12
#define NN 4000
#define NE 64000
#define GH 32
#define LH 64
#define BT (NB*NT)        // 192
#define NSEQ (NB*NN)      // 64000
#define NNZ (NE+NN)       // 68000

// ---- device-global scratch (avoids ws_size uncertainty) ----
__device__ float g_deg[NN];
__device__ float g_dis[NN];
__device__ int   g_cnt[NN];
__device__ int   g_rowptr[NN+1];
__device__ int   g_pos[NN];
__device__ int   g_col[NNZ];
__device__ float g_val[NNZ];
__device__ float g_xT[NN*BT];                       // 3 MB  [n][bt]
__device__ float g_h1[(size_t)NN*BT*GH];            // 98 MB [n][bt][c]
__device__ float g_h2[(size_t)NN*BT*GH];            // 98 MB [n][bt][c]
__device__ float g_Wpack[96*LH*4];                  // [k][j][gate]
__device__ float g_biasC[LH*4];                     // [j][gate]

__device__ __forceinline__ float sgm(float x){ return 1.f/(1.f+__expf(-x)); }
__device__ __forceinline__ float tfast(float x){
  x = fminf(15.f, fmaxf(-15.f, x));
  float e = __expf(2.f*x);
  return (e-1.f)/(e+1.f);
}

#define FMA4(acc, wv, xs) do{ (acc).x=fmaf((wv).x,(xs),(acc).x); (acc).y=fmaf((wv).y,(xs),(acc).y); \
                              (acc).z=fmaf((wv).z,(xs),(acc).z); (acc).w=fmaf((wv).w,(xs),(acc).w);}while(0)

// ---------------- graph preprocessing ----------------
__global__ void k_init(){
  int n = blockIdx.x*blockDim.x + threadIdx.x;
  if (n < NN){ g_deg[n] = 1.0f; g_cnt[n] = 1; }   // self loop
}

__global__ void k_count(const int* __restrict__ ei, const float* __restrict__ ew){
  int e = blockIdx.x*blockDim.x + threadIdx.x;
  if (e < NE){
    int d = ei[NE + e];
    atomicAdd(&g_deg[d], ew[e]);
    atomicAdd(&g_cnt[d], 1);
  }
}

__global__ void k_scan(){
  __shared__ int sd[1024];
  int tid = threadIdx.x;
  int base = tid*4;
  int v0=0,v1=0,v2=0,v3=0;
  if (base+0 < NN) v0 = g_cnt[base+0];
  if (base+1 < NN) v1 = g_cnt[base+1];
  if (base+2 < NN) v2 = g_cnt[base+2];
  if (base+3 < NN) v3 = g_cnt[base+3];
  int sum = v0+v1+v2+v3;
  sd[tid] = sum; __syncthreads();
  for (int off=1; off<1024; off<<=1){
    int x = (tid>=off) ? sd[tid-off] : 0;
    __syncthreads();
    sd[tid] += x;
    __syncthreads();
  }
  int run = sd[tid] - sum;           // exclusive prefix
  if (base+0 < NN){ g_rowptr[base+0]=run; g_pos[base+0]=run+1; } run += v0;
  if (base+1 < NN){ g_rowptr[base+1]=run; g_pos[base+1]=run+1; } run += v1;
  if (base+2 < NN){ g_rowptr[base+2]=run; g_pos[base+2]=run+1; } run += v2;
  if (base+3 < NN){ g_rowptr[base+3]=run; g_pos[base+3]=run+1; } run += v3;
  if (tid == 1023) g_rowptr[NN] = sd[1023];
  for (int i = tid; i < NN; i += 1024) g_dis[i] = rsqrtf(g_deg[i]);
}

__global__ void k_fill(const int* __restrict__ ei, const float* __restrict__ ew){
  int t = blockIdx.x*blockDim.x + threadIdx.x;
  if (t < NN){
    int p = g_rowptr[t];
    g_col[p] = t;
    g_val[p] = g_dis[t]*g_dis[t];
  } else if (t < NN+NE){
    int e = t - NN;
    int s = ei[e], d = ei[NE+e];
    int p = atomicAdd(&g_pos[d], 1);
    g_col[p] = s;
    g_val[p] = g_dis[s]*ew[e]*g_dis[d];
  }
}

__global__ void k_wprep(const float* __restrict__ Wih, const float* __restrict__ Whh,
                        const float* __restrict__ bih, const float* __restrict__ bhh){
  int t = blockIdx.x*blockDim.x + threadIdx.x;
  if (t < 96*256){
    int k = t >> 8; int r = t & 255; int j = r >> 2; int g = r & 3;
    int row = g*64 + j;
    g_Wpack[t] = (k < 32) ? Wih[row*32 + k] : Whh[row*64 + (k-32)];
  }
  if (t < 256){
    int j = t >> 2, g = t & 3;
    g_biasC[t] = bih[g*64+j] + bhh[g*64+j];
  }
}

// x [bt=192][n=4000] -> xT [n][bt]
__global__ void k_transpose(const float* __restrict__ x){
  __shared__ float tile[32][33];
  int n0 = blockIdx.x*32, bt0 = blockIdx.y*32;
  int tx = threadIdx.x, ty = threadIdx.y;
  tile[ty][tx] = x[(size_t)(bt0+ty)*NN + n0 + tx];
  __syncthreads();
  g_xT[(size_t)(n0+ty)*BT + bt0 + tx] = tile[tx][ty];
}

// layer1: y = A@x (scalar), h1 = relu(y*W1 + b1)
__global__ void k_prop1(const float* __restrict__ W1, const float* __restrict__ b1){
  int dst = blockIdx.x;
  int bt  = threadIdx.x;   // 192
  int beg = g_rowptr[dst], end = g_rowptr[dst+1];
  float y = 0.f;
  for (int e = beg; e < end; ++e)
    y = fmaf(g_val[e], g_xT[(size_t)g_col[e]*BT + bt], y);
  float* o = &g_h1[((size_t)dst*BT + bt)*GH];
  #pragma unroll
  for (int c = 0; c < GH; ++c)
    o[c] = fmaxf(fmaf(y, W1[c], b1[c]), 0.f);
}

// layer2: p = A@h1 (32 ch), h2 = relu(p@W2 + b2)
__global__ void __launch_bounds__(256) k_prop2(const float* __restrict__ W2, const float* __restrict__ b2){
  int dst = blockIdx.x;
  int btc = blockIdx.y;
  int c = threadIdx.x & 31;
  int g = threadIdx.x >> 5;       // 0..7
  int bt = btc*8 + g;
  int beg = g_rowptr[dst], end = g_rowptr[dst+1];
  float p = 0.f;
  for (int e = beg; e < end; ++e){
    int s = g_col[e]; float v = g_val[e];
    p = fmaf(v, g_h1[((size_t)s*BT + bt)*GH + c], p);
  }
  __shared__ float pl[256];
  pl[threadIdx.x] = p;
  __syncthreads();
  float w2c[32];
  #pragma unroll
  for (int k = 0; k < 32; ++k) w2c[k] = W2[k*GH + c];
  float acc = b2[c];
  #pragma unroll
  for (int k = 0; k < 32; ++k) acc = fmaf(pl[(g<<5)|k], w2c[k], acc);
  g_h2[((size_t)dst*BT + bt)*GH + c] = fmaxf(acc, 0.f);
}

// fused LSTM (T=12, LH=64) + FC. 1 wave = 1 hidden-unit-slice of 8 sequences.
__global__ void __launch_bounds__(1024) k_lstm(const float* __restrict__ Wfc,
                                               const float* __restrict__ bfc,
                                               float* __restrict__ out){
  __shared__ float4 sW[96*64];                    // 96 KB  [k][j] -> 4 gates
  __shared__ float4 sX[1024];                     // 16 KB  [seq128][8quads]
  __shared__ __align__(16) float sH[128*64];      // 32 KB  [seq128][64]
  int tid = threadIdx.x; int w = tid >> 6; int j = tid & 63;
  const float4* Wp4 = (const float4*)g_Wpack;
  for (int i = tid; i < 96*64; i += 1024) sW[i] = Wp4[i];
  float4 bias4 = ((const float4*)g_biasC)[j];
  float wfc = Wfc[j], bf = bfc[0];

  int q0 = blockIdx.x * 128;
  int qs = q0 + (tid >> 3);
  int bs = qs / NN; int ns = qs - bs*NN;
  const float4* xsrc = (const float4*)(g_h2 + ((size_t)ns*BT + bs*NT)*GH) + (tid & 7);

  float c8[8], h8[8];
  #pragma unroll
  for (int s = 0; s < 8; ++s){ c8[s]=0.f; h8[s]=0.f; sH[(w*8+s)*64 + j] = 0.f; }
  __syncthreads();

  for (int t = 0; t < NT; ++t){
    sX[tid] = xsrc[t*8];
    __syncthreads();
    float4 g4[8];
    #pragma unroll
    for (int s = 0; s < 8; ++s) g4[s] = bias4;
    // x part: k = 0..31
    #pragma unroll
    for (int kq = 0; kq < 8; ++kq){
      float4 w0 = sW[(kq*4+0)*64 + j];
      float4 w1 = sW[(kq*4+1)*64 + j];
      float4 w2 = sW[(kq*4+2)*64 + j];
      float4 w3 = sW[(kq*4+3)*64 + j];
      #pragma unroll
      for (int s = 0; s < 8; ++s){
        float4 xv = sX[(w*8+s)*8 + kq];
        FMA4(g4[s], w0, xv.x); FMA4(g4[s], w1, xv.y);
        FMA4(g4[s], w2, xv.z); FMA4(g4[s], w3, xv.w);
      }
    }
    // h part: k = 32..95
    #pragma unroll
    for (int kq = 0; kq < 16; ++kq){
      float4 w0 = sW[(32+kq*4+0)*64 + j];
      float4 w1 = sW[(32+kq*4+1)*64 + j];
      float4 w2 = sW[(32+kq*4+2)*64 + j];
      float4 w3 = sW[(32+kq*4+3)*64 + j];
      #pragma unroll
      for (int s = 0; s < 8; ++s){
        float4 hv = *(const float4*)&sH[(w*8+s)*64 + kq*4];
        FMA4(g4[s], w0, hv.x); FMA4(g4[s], w1, hv.y);
        FMA4(g4[s], w2, hv.z); FMA4(g4[s], w3, hv.w);
      }
    }
    #pragma unroll
    for (int s = 0; s < 8; ++s){
      float ii = sgm(g4[s].x);
      float ff = sgm(g4[s].y);
      float gg = tfast(g4[s].z);
      float oo = sgm(g4[s].w);
      float cc = fmaf(ff, c8[s], ii*gg);
      c8[s] = cc;
      float hn = oo * tfast(cc);
      h8[s] = hn;
      sH[(w*8+s)*64 + j] = hn;
    }
    __syncthreads();
  }
  #pragma unroll
  for (int s = 0; s < 8; ++s){
    float v = h8[s]*wfc;
    v += __shfl_xor(v,32); v += __shfl_xor(v,16); v += __shfl_xor(v,8);
    v += __shfl_xor(v,4);  v += __shfl_xor(v,2);  v += __shfl_xor(v,1);
    if (j == 0) out[q0 + w*8 + s] = v + bf;
  }
}

extern "C" void kernel_launch(void* const* d_in, const int* in_sizes, int n_in,
                              void* d_out, int out_size, void* d_ws, size_t ws_size,
                              hipStream_t stream) {
  const float* x_seq = (const float*)d_in[0];
  const int*   ei    = (const int*)  d_in[1];
  const float* ew    = (const float*)d_in[2];
  const float* W1    = (const float*)d_in[3];
  const float* b1    = (const float*)d_in[4];
  const float* W2    = (const float*)d_in[5];
  const float* b2    = (const float*)d_in[6];
  const float* Wih   = (const float*)d_in[7];
  const float* Whh   = (const float*)d_in[8];
  const float* bih   = (const float*)d_in[9];
  const float* bhh   = (const float*)d_in[10];
  const float* Wfc   = (const float*)d_in[11];
  const float* bfc   = (const float*)d_in[12];
  float* out = (float*)d_out;

  k_init <<<(NN+255)/256, 256, 0, stream>>>();
  k_count<<<(NE+255)/256, 256, 0, stream>>>(ei, ew);
  k_scan <<<1, 1024, 0, stream>>>();
  k_fill <<<(NN+NE+255)/256, 256, 0, stream>>>(ei, ew);
  k_wprep<<<(96*256+255)/256, 256, 0, stream>>>(Wih, Whh, bih, bhh);
  k_transpose<<<dim3(125,6), dim3(32,32), 0, stream>>>(x_seq);
  k_prop1<<<NN, 192, 0, stream>>>(W1, b1);
  k_prop2<<<dim3(NN,24), 256, 0, stream>>>(W2, b2);
  k_lstm <<<500, 1024, 0, stream>>>(Wfc, bfc, out);
}